// Round 10
// baseline (121.612 us; speedup 1.0000x reference)
//
#include <hip/hip_runtime.h>
#include <math.h>

#define NT 256
#define L_LEN 720
#define NROWS (64 * 321)   // 20544, divisible by 4

#define LOG2E 1.4426950408889634f
#define LN2   0.6931471805599453f

// force a (uniform) float into an SGPR so it costs no VGPR and v_fma can use
// it as the single legal scalar operand
__device__ __forceinline__ float rfl(float v) {
    return __int_as_float(__builtin_amdgcn_readfirstlane(__float_as_int(v)));
}

__global__ __launch_bounds__(NT, 8) void trend_kernel(
    const float* __restrict__ x,
    const float* __restrict__ cw0, const float* __restrict__ cb0,
    const float* __restrict__ cw1, const float* __restrict__ cb1,
    const float* __restrict__ cw2, const float* __restrict__ cb2,
    const float* __restrict__ cw3, const float* __restrict__ cb3,
    const float* __restrict__ W1, const float* __restrict__ b1,
    const float* __restrict__ W2, const float* __restrict__ b2,
    float* __restrict__ out)
{
    // one wave per row; 4 independent waves per block; no LDS, no barriers.
    // All conv weights live in SGPRs (readfirstlane) pre-scaled by LOG2E, so
    // the VGPR live set is ~50 -> 8 waves/SIMD under __launch_bounds__(256,8)
    // WITHOUT the R7 spill storm (which had the 40 weights in VGPRs).
    const int lane = threadIdx.x & 63;
    const int wid  = threadIdx.x >> 6;
    const int row  = blockIdx.x * 4 + wid;

    const float* __restrict__ xr = x + (size_t)row * L_LEN;

    const float* cws[4] = {cw0, cw1, cw2, cw3};
    const float* cbs[4] = {cb0, cb1, cb2, cb3};
    // w2 = w * log2e, bs2 = bias * log2e  (conv then directly yields u = f*log2e)
    float w2[4][9], bs2[4];
#pragma unroll
    for (int s = 0; s < 4; ++s) {
        const int k = 3 + 2 * s;
        bs2[s] = rfl(cbs[s][0] * LOG2E);
#pragma unroll
        for (int t = 0; t < 9; ++t)
            w2[s][t] = (t < k) ? rfl(cws[s][t] * LOG2E) : 0.0f;
    }

    // lane t owns elements 12t .. 12t+11 ; lanes 60..63 idle (60*12 == 720)
    const bool active = lane < 60;

    float xw[20];                          // x[12*lane-4 .. 12*lane+15]
    float S[4]  = {0.f, 0.f, 0.f, 0.f};    // sum 2^u
    float Tu[4] = {0.f, 0.f, 0.f, 0.f};    // sum u*2^u

    if (active) {
        const int e0 = 12 * lane - 4;
#pragma unroll
        for (int q = 0; q < 5; ++q) {
            int e = e0 + 4 * q;
            e = (e < 0) ? 0 : ((e > L_LEN - 4) ? (L_LEN - 4) : e);  // 16B-aligned
            float4 v = *(const float4*)(xr + e);
            xw[4 * q + 0] = v.x; xw[4 * q + 1] = v.y;
            xw[4 * q + 2] = v.z; xw[4 * q + 3] = v.w;
        }
        if (lane == 0)  { xw[0] = 0.f; xw[1] = 0.f; xw[2] = 0.f; xw[3] = 0.f; }
        if (lane == 59) { xw[16] = 0.f; xw[17] = 0.f; xw[18] = 0.f; xw[19] = 0.f; }

        // pin: loaded exactly once, never re-fetched/rematerialized
#pragma unroll
        for (int t = 0; t < 20; ++t) asm volatile("" : "+v"(xw[t]));

        // fused: conv(u) -> 2^u -> accumulate S, Tu. 36 wave-inst/element.
#pragma unroll
        for (int e = 0; e < 12; ++e) {
#pragma unroll
            for (int s = 0; s < 4; ++s) {
                const int k = 3 + 2 * s;
                const int off = 3 - s;          // 4 - k/2
                float u = bs2[s];
#pragma unroll
                for (int t = 0; t < k; ++t)
                    u = fmaf(w2[s][t], xw[e + off + t], u);
                float ev = __builtin_amdgcn_exp2f(u);
                S[s]  += ev;
                Tu[s]  = fmaf(u, ev, Tu[s]);
            }
        }
    }

    // wave-wide butterfly reduce (8 independent chains)
#pragma unroll
    for (int s = 0; s < 4; ++s) {
#pragma unroll
        for (int off = 32; off; off >>= 1) {
            S[s]  += __shfl_xor(S[s],  off);
            Tu[s] += __shfl_xor(Tu[s], off);
        }
    }

    // entropy = ln S - T/S = ln2 * (log2 S - Tu/S)
    float ent[4];
#pragma unroll
    for (int s = 0; s < 4; ++s)
        ent[s] = LN2 * (__builtin_amdgcn_logf(S[s])
                        - Tu[s] * __builtin_amdgcn_rcpf(S[s]));

    // MLP: hidden unit per lane (mod 32); logits via 32-lane shuffle reduce
    const int hidx = lane & 31;
    float h = b1[hidx];
#pragma unroll
    for (int s = 0; s < 4; ++s) h = fmaf(ent[s], W1[s * 32 + hidx], h);
    h = fmaxf(h, 0.0f);

    const float4 w2v = ((const float4*)W2)[hidx];
    float lg[4] = {h * w2v.x, h * w2v.y, h * w2v.z, h * w2v.w};
#pragma unroll
    for (int c = 0; c < 4; ++c) {
#pragma unroll
        for (int off = 16; off; off >>= 1)
            lg[c] += __shfl_xor(lg[c], off);
    }
    lg[0] += b2[0]; lg[1] += b2[1]; lg[2] += b2[2]; lg[3] += b2[3];

    float m = fmaxf(fmaxf(lg[0], lg[1]), fmaxf(lg[2], lg[3]));
    float e0w = __expf(lg[0] - m), e1w = __expf(lg[1] - m);
    float e2w = __expf(lg[2] - m), e3w = __expf(lg[3] - m);
    float inv = 1.0f / (e0w + e1w + e2w + e3w);
    const float wgt[4] = {e0w * inv, e1w * inv, e2w * inv, e3w * inv};

    // merged 9-tap output kernel from the LOG2E-scaled weights, rescaled by LN2
    float Wm[9] = {0,0,0,0,0,0,0,0,0};
    float Bm = 0.f;
#pragma unroll
    for (int s = 0; s < 4; ++s) {
        const int k = 3 + 2 * s;
        const int off = 3 - s;
#pragma unroll
        for (int t = 0; t < k; ++t)
            Wm[off + t] = fmaf(wgt[s], w2[s][t], Wm[off + t]);
        Bm = fmaf(wgt[s], bs2[s], Bm);
    }
#pragma unroll
    for (int j = 0; j < 9; ++j) Wm[j] *= LN2;
    Bm *= LN2;

    // output: merged conv from the pinned window, float4 stores
    if (active) {
        float* __restrict__ orow = out + (size_t)row * L_LEN + 12 * lane;
#pragma unroll
        for (int q = 0; q < 3; ++q) {
            float4 v;
#pragma unroll
            for (int c = 0; c < 4; ++c) {
                const int e = 4 * q + c;
                float acc = Bm;
#pragma unroll
                for (int j = 0; j < 9; ++j)
                    acc = fmaf(Wm[j], xw[e + j], acc);
                ((float*)&v)[c] = acc;
            }
            *(float4*)(orow + 4 * q) = v;
        }
    }
}

extern "C" void kernel_launch(void* const* d_in, const int* in_sizes, int n_in,
                              void* d_out, int out_size, void* d_ws, size_t ws_size,
                              hipStream_t stream) {
    const float* xp  = (const float*)d_in[0];
    const float* cw0 = (const float*)d_in[1];
    const float* cb0 = (const float*)d_in[2];
    const float* cw1 = (const float*)d_in[3];
    const float* cb1 = (const float*)d_in[4];
    const float* cw2 = (const float*)d_in[5];
    const float* cb2 = (const float*)d_in[6];
    const float* cw3 = (const float*)d_in[7];
    const float* cb3 = (const float*)d_in[8];
    const float* W1  = (const float*)d_in[9];
    const float* b1  = (const float*)d_in[10];
    const float* W2  = (const float*)d_in[11];
    const float* b2  = (const float*)d_in[12];
    float* outp = (float*)d_out;

    trend_kernel<<<NROWS / 4, NT, 0, stream>>>(xp, cw0, cb0, cw1, cb1, cw2, cb2,
                                               cw3, cb3, W1, b1, W2, b2, outp);
}

// Round 11
// 36.536 us; speedup vs baseline: 3.3285x; 3.3285x over previous
//
#include <hip/hip_runtime.h>
#include <math.h>

#define NT 256
#define L_LEN 720
#define NROWS (64 * 321)   // 20544, divisible by 4

#define LOG2E 1.4426950408889634f
#define LN2   0.6931471805599453f

// ---- DPP wave reductions: pure VALU pipe, no LDS, no lgkmcnt stalls ----
template<int CTRL, int RM>
__device__ __forceinline__ float dpp_add(float x) {
    int t = __builtin_amdgcn_update_dpp(0, __float_as_int(x), CTRL, RM, 0xf, true);
    return x + __int_as_float(t);
}

// full-wave (64 lane) sum -> uniform SGPR value
__device__ __forceinline__ float wave_sum64(float x) {
    x = dpp_add<0x111, 0xf>(x);   // row_shr:1
    x = dpp_add<0x112, 0xf>(x);   // row_shr:2
    x = dpp_add<0x114, 0xf>(x);   // row_shr:4
    x = dpp_add<0x118, 0xf>(x);   // row_shr:8  -> lane15 of each row = row total
    x = dpp_add<0x142, 0xa>(x);   // row_bcast:15 into rows 1,3
    x = dpp_add<0x143, 0xc>(x);   // row_bcast:31 into rows 2,3 -> lane63 = total
    return __int_as_float(__builtin_amdgcn_readlane(__float_as_int(x), 63));
}

// 32-lane sum (lanes 0..31; upper half mirrors) -> uniform SGPR value
__device__ __forceinline__ float half_sum32(float x) {
    x = dpp_add<0x111, 0xf>(x);
    x = dpp_add<0x112, 0xf>(x);
    x = dpp_add<0x114, 0xf>(x);
    x = dpp_add<0x118, 0xf>(x);
    x = dpp_add<0x142, 0xa>(x);   // lane31 = sum of lanes 0..31
    return __int_as_float(__builtin_amdgcn_readlane(__float_as_int(x), 31));
}

__global__ __launch_bounds__(NT, 4) void trend_kernel(
    const float* __restrict__ x,
    const float* __restrict__ cw0, const float* __restrict__ cb0,
    const float* __restrict__ cw1, const float* __restrict__ cb1,
    const float* __restrict__ cw2, const float* __restrict__ cb2,
    const float* __restrict__ cw3, const float* __restrict__ cb3,
    const float* __restrict__ W1, const float* __restrict__ b1,
    const float* __restrict__ W2, const float* __restrict__ b2,
    float* __restrict__ out)
{
    // one wave per row; 4 independent waves per block; no LDS, no barriers,
    // and — this round — ZERO ds_bpermute: all reductions are DPP (VALU).
    const int lane = threadIdx.x & 63;
    const int wid  = threadIdx.x >> 6;
    const int row  = blockIdx.x * 4 + wid;

    const float* __restrict__ xr = x + (size_t)row * L_LEN;

    // conv weights pre-scaled by LOG2E (conv directly yields u = f*log2e)
    const float* cws[4] = {cw0, cw1, cw2, cw3};
    const float* cbs[4] = {cb0, cb1, cb2, cb3};
    float w2[4][9], bs2[4];
#pragma unroll
    for (int s = 0; s < 4; ++s) {
        const int k = 3 + 2 * s;
        bs2[s] = cbs[s][0] * LOG2E;
#pragma unroll
        for (int t = 0; t < 9; ++t)
            w2[s][t] = (t < k) ? (cws[s][t] * LOG2E) : 0.0f;
    }

    // lane t owns elements 12t .. 12t+11 ; lanes 60..63 idle (60*12 == 720)
    const bool active = lane < 60;

    float xw[20];                          // x[12*lane-4 .. 12*lane+15]
    float S[4]  = {0.f, 0.f, 0.f, 0.f};    // sum 2^u
    float Tu[4] = {0.f, 0.f, 0.f, 0.f};    // sum u*2^u

    if (active) {
        const int e0 = 12 * lane - 4;
#pragma unroll
        for (int q = 0; q < 5; ++q) {
            int e = e0 + 4 * q;
            e = (e < 0) ? 0 : ((e > L_LEN - 4) ? (L_LEN - 4) : e);  // 16B-aligned
            float4 v = *(const float4*)(xr + e);
            xw[4 * q + 0] = v.x; xw[4 * q + 1] = v.y;
            xw[4 * q + 2] = v.z; xw[4 * q + 3] = v.w;
        }
        if (lane == 0)  { xw[0] = 0.f; xw[1] = 0.f; xw[2] = 0.f; xw[3] = 0.f; }
        if (lane == 59) { xw[16] = 0.f; xw[17] = 0.f; xw[18] = 0.f; xw[19] = 0.f; }

        // pin: loaded exactly once, never re-fetched/rematerialized
#pragma unroll
        for (int t = 0; t < 20; ++t) asm volatile("" : "+v"(xw[t]));

        // fused: conv(u) -> 2^u -> accumulate S, Tu
#pragma unroll
        for (int e = 0; e < 12; ++e) {
#pragma unroll
            for (int s = 0; s < 4; ++s) {
                const int k = 3 + 2 * s;
                const int off = 3 - s;          // 4 - k/2
                float u = bs2[s];
#pragma unroll
                for (int t = 0; t < k; ++t)
                    u = fmaf(w2[s][t], xw[e + off + t], u);
                float ev = __builtin_amdgcn_exp2f(u);
                S[s]  += ev;
                Tu[s]  = fmaf(u, ev, Tu[s]);
            }
        }
    }

    // wave-wide totals via DPP; entropy = ln2 * (log2 S - Tu/S), wave-uniform
    float ent[4];
#pragma unroll
    for (int s = 0; s < 4; ++s) {
        float Sg = wave_sum64(S[s]);
        float Tg = wave_sum64(Tu[s]);
        ent[s] = LN2 * (__builtin_amdgcn_logf(Sg)
                        - Tg * __builtin_amdgcn_rcpf(Sg));
    }

    // MLP: hidden unit per lane (mod 32); logits via DPP 32-lane sums
    const int hidx = lane & 31;
    float h = b1[hidx];
#pragma unroll
    for (int s = 0; s < 4; ++s) h = fmaf(ent[s], W1[s * 32 + hidx], h);
    h = fmaxf(h, 0.0f);

    const float4 w2v = ((const float4*)W2)[hidx];
    float lg[4];
    lg[0] = half_sum32(h * w2v.x) + b2[0];
    lg[1] = half_sum32(h * w2v.y) + b2[1];
    lg[2] = half_sum32(h * w2v.z) + b2[2];
    lg[3] = half_sum32(h * w2v.w) + b2[3];

    // softmax (wave-uniform), LN2 folded into the mixing weights
    float m = fmaxf(fmaxf(lg[0], lg[1]), fmaxf(lg[2], lg[3]));
    float e0w = __expf(lg[0] - m), e1w = __expf(lg[1] - m);
    float e2w = __expf(lg[2] - m), e3w = __expf(lg[3] - m);
    float inv = LN2 / (e0w + e1w + e2w + e3w);
    const float wgt[4] = {e0w * inv, e1w * inv, e2w * inv, e3w * inv};

    // merged 9-tap output kernel (w2 are LOG2E-scaled; wgt carries the LN2)
    float Wm[9] = {0,0,0,0,0,0,0,0,0};
    float Bm = 0.f;
#pragma unroll
    for (int s = 0; s < 4; ++s) {
        const int k = 3 + 2 * s;
        const int off = 3 - s;
#pragma unroll
        for (int t = 0; t < k; ++t)
            Wm[off + t] = fmaf(wgt[s], w2[s][t], Wm[off + t]);
        Bm = fmaf(wgt[s], bs2[s], Bm);
    }

    // output: merged conv from the pinned window, float4 stores
    if (active) {
        float* __restrict__ orow = out + (size_t)row * L_LEN + 12 * lane;
#pragma unroll
        for (int q = 0; q < 3; ++q) {
            float4 v;
#pragma unroll
            for (int c = 0; c < 4; ++c) {
                const int e = 4 * q + c;
                float acc = Bm;
#pragma unroll
                for (int j = 0; j < 9; ++j)
                    acc = fmaf(Wm[j], xw[e + j], acc);
                ((float*)&v)[c] = acc;
            }
            *(float4*)(orow + 4 * q) = v;
        }
    }
}

extern "C" void kernel_launch(void* const* d_in, const int* in_sizes, int n_in,
                              void* d_out, int out_size, void* d_ws, size_t ws_size,
                              hipStream_t stream) {
    const float* xp  = (const float*)d_in[0];
    const float* cw0 = (const float*)d_in[1];
    const float* cb0 = (const float*)d_in[2];
    const float* cw1 = (const float*)d_in[3];
    const float* cb1 = (const float*)d_in[4];
    const float* cw2 = (const float*)d_in[5];
    const float* cb2 = (const float*)d_in[6];
    const float* cw3 = (const float*)d_in[7];
    const float* cb3 = (const float*)d_in[8];
    const float* W1  = (const float*)d_in[9];
    const float* b1  = (const float*)d_in[10];
    const float* W2  = (const float*)d_in[11];
    const float* b2  = (const float*)d_in[12];
    float* outp = (float*)d_out;

    trend_kernel<<<NROWS / 4, NT, 0, stream>>>(xp, cw0, cb0, cw1, cb1, cw2, cb2,
                                               cw3, cb3, W1, b1, W2, b2, outp);
}